// Round 3
// baseline (159.870 us; speedup 1.0000x reference)
//
#include <hip/hip_runtime.h>
#include <math.h>

#define DIM 128
#define PSTRIDE 132          // per-partial floats: l, pad3, acc[128] (16B-aligned acc)
#define NEG_BIG (-3.0e38f)

// ---------------------------------------------------------------------------
// Phase A: logits. Each 32-lane group owns a strided row stream. Lane vlane
// holds float4 elements [4v..4v+3]. Per row: L1 distance via 5-step shfl_xor
// reduce, store -dist to logits[]. NO loop-carried state -> deep pipelining.
// Global max via atomicMin on the float bit pattern (all logits <= 0, so
// min-uint == max-float; commutative+idempotent => bitwise deterministic).
// ---------------------------------------------------------------------------
__global__ __launch_bounds__(256) void nd_logits(const float* __restrict__ query,
                                                 const float* __restrict__ keys,
                                                 float* __restrict__ logits,
                                                 unsigned int* __restrict__ maxbits,
                                                 int nrows, int P) {
    const int tid   = threadIdx.x;
    const int lane  = tid & 63;
    const int vlane = lane & 31;
    const int half  = lane >> 5;
    const int p     = blockIdx.x * (blockDim.x >> 6) + (tid >> 6);
    const int S     = 2 * P;
    const int strm  = 2 * p + half;

    const float4 q = *reinterpret_cast<const float4*>(query + vlane * 4);
    float wmax = NEG_BIG;

    for (int row = strm; row < nrows; row += S) {
        const float4 kv = *reinterpret_cast<const float4*>(keys + (size_t)row * DIM + vlane * 4);
        float s = fabsf(kv.x - q.x) + fabsf(kv.y - q.y)
                + fabsf(kv.z - q.z) + fabsf(kv.w - q.w);
        #pragma unroll
        for (int off = 16; off > 0; off >>= 1)
            s += __shfl_xor(s, off, 64);              // stays within 32-lane group
        const float lg = -s;
        wmax = fmaxf(wmax, lg);
        if (vlane == 0) logits[row] = lg;
    }

    wmax = fmaxf(wmax, __shfl_xor(wmax, 32, 64));
    if (lane == 0) atomicMin(maxbits, __float_as_uint(wmax));
}

// ---------------------------------------------------------------------------
// Phase C: weighted value accumulation with the FIXED global max M.
// Per row: w = exp(logit - M); acc4 += w*v4; l += w. No cross-lane ops in the
// loop, no rescales -> pure streaming FMA, BW-bound.
// ---------------------------------------------------------------------------
__global__ __launch_bounds__(256) void nd_accum(const float* __restrict__ values,
                                                const float* __restrict__ logits,
                                                const unsigned int* __restrict__ maxbits,
                                                float* __restrict__ part,
                                                int nrows, int P) {
    const int tid   = threadIdx.x;
    const int lane  = tid & 63;
    const int vlane = lane & 31;
    const int half  = lane >> 5;
    const int p     = blockIdx.x * (blockDim.x >> 6) + (tid >> 6);
    const int S     = 2 * P;
    const int strm  = 2 * p + half;

    const float M = __uint_as_float(*maxbits);
    float4 acc = make_float4(0.f, 0.f, 0.f, 0.f);
    float  l = 0.f;

    for (int row = strm; row < nrows; row += S) {
        const float4 vv = *reinterpret_cast<const float4*>(values + (size_t)row * DIM + vlane * 4);
        const float w = __expf(logits[row] - M);      // uniform within group
        l += w;
        acc.x += w * vv.x;
        acc.y += w * vv.y;
        acc.z += w * vv.z;
        acc.w += w * vv.w;
    }

    // Merge the wave's two groups (same columns, different rows): plain sums.
    acc.x += __shfl_xor(acc.x, 32, 64);
    acc.y += __shfl_xor(acc.y, 32, 64);
    acc.z += __shfl_xor(acc.z, 32, 64);
    acc.w += __shfl_xor(acc.w, 32, 64);
    l     += __shfl_xor(l,     32, 64);

    float* wp = part + (size_t)p * PSTRIDE;
    if (lane == 0) wp[0] = l;
    if (half == 0)
        *reinterpret_cast<float4*>(wp + 4 + vlane * 4) = acc;
}

// ---------------------------------------------------------------------------
// Merge 64 consecutive partials into one (plain sums).
// ---------------------------------------------------------------------------
__global__ __launch_bounds__(256) void nd_merge(const float* __restrict__ part,
                                                float* __restrict__ part2) {
    __shared__ float sh_red[256];
    __shared__ float shL;
    const int tid  = threadIdx.x;
    const int base = blockIdx.x * 64;

    if (tid < 64) {
        float lp = part[(size_t)(base + tid) * PSTRIDE];
        #pragma unroll
        for (int off = 32; off > 0; off >>= 1)
            lp += __shfl_xor(lp, off, 64);
        if (tid == 0) shL = lp;
    }

    const int d = tid & 127, g = tid >> 7;
    float o = 0.f;
    for (int p = g; p < 64; p += 2)
        o += part[(size_t)(base + p) * PSTRIDE + 4 + d];
    sh_red[tid] = o;
    __syncthreads();

    if (tid < 128) {
        float* wp = part2 + (size_t)blockIdx.x * PSTRIDE;
        if (tid == 0) wp[0] = shL;
        wp[4 + tid] = sh_red[tid] + sh_red[tid + 128];
    }
}

// ---------------------------------------------------------------------------
// Final: sum the B2 (<=128) level-2 partials, normalize, write out[128].
// ---------------------------------------------------------------------------
__global__ __launch_bounds__(256) void nd_final(const float* __restrict__ part2,
                                                float* __restrict__ out, int B2) {
    __shared__ float sh_red[256];
    __shared__ float shL;
    const int tid = threadIdx.x;

    if (tid < 64) {
        float lp = 0.f;
        for (int p = tid; p < B2; p += 64)
            lp += part2[(size_t)p * PSTRIDE];
        #pragma unroll
        for (int off = 32; off > 0; off >>= 1)
            lp += __shfl_xor(lp, off, 64);
        if (tid == 0) shL = lp;
    }

    const int d = tid & 127, g = tid >> 7;
    float o = 0.f;
    for (int p = g; p < B2; p += 2)
        o += part2[(size_t)p * PSTRIDE + 4 + d];
    sh_red[tid] = o;
    __syncthreads();

    if (tid < 128)
        out[tid] = (sh_red[tid] + sh_red[tid + 128]) / shL;
}

extern "C" void kernel_launch(void* const* d_in, const int* in_sizes, int n_in,
                              void* d_out, int out_size, void* d_ws, size_t ws_size,
                              hipStream_t stream) {
    const float* query  = (const float*)d_in[0];
    const float* keys   = (const float*)d_in[1];
    const float* values = (const float*)d_in[2];
    float* out = (float*)d_out;
    float* ws  = (float*)d_ws;

    const int nrows = in_sizes[1] / DIM;
    const int LN    = (nrows + 63) & ~63;            // logits region (floats)

    int P = 8192;                                    // waves in A and C
    const size_t capf = ws_size / sizeof(float);
    while ((size_t)LN + 16 + (size_t)(P + P / 64) * PSTRIDE > capf && P > 512)
        P >>= 1;
    const int B2 = P / 64;

    float*        logits  = ws;
    unsigned int* maxbits = (unsigned int*)(ws + LN);
    float*        part    = ws + LN + 16;
    float*        part2   = part + (size_t)P * PSTRIDE;

    hipMemsetAsync(maxbits, 0xFF, sizeof(unsigned int), stream);  // UINT_MAX seed
    nd_logits<<<P / 4, 256, 0, stream>>>(query, keys, logits, maxbits, nrows, P);
    nd_accum <<<P / 4, 256, 0, stream>>>(values, logits, maxbits, part, nrows, P);
    nd_merge <<<B2,    256, 0, stream>>>(part, part2);
    nd_final <<<1,     256, 0, stream>>>(part2, out, B2);
}